// Round 8
// baseline (200.659 us; speedup 1.0000x reference)
//
#include <hip/hip_runtime.h>
#include <math.h>

#define NC 100
#define ND 384
#define NB 4096
#define KS 8                         // dim-split: 8 blocks of 48 dims
#define KT 48
#define MT 128                       // samples per gemm block
#define XSP 52                       // xs row pad (13 float4)
#define CLS_PAD 132                  // d-major class row pad (16B-aligned b128)
#define PPR 100                      // partial row (exactly NC floats, 400 B)
#define GEMM_BLOCKS 256              // 32 mb-groups x 8 ks
#define GRID (GEMM_BLOCKS + NC)      // 356 <= 512 resident slots -> spin-safe
#define MAGIC 0x5F3C2A11u
#define SAF (MT * XSP + 2 * KT * CLS_PAD + 112)  // 19440 floats = 77.8 KB -> 2 blocks/CU

// ONE kernel. Block roles:
//  [0,256)    gemm (mb=b>>3, ks=b&7): partial d2 (incl. per-dim w*c^2 term ->
//             no tcc array) for 128 samples x 100 classes over dims
//             [ks*48,+48). After writing partials: fence + flag. The ks==7
//             block of each mb-group then builds the presence mask, polls the
//             7 sibling flags + 100 cdist flags (all poll-ees are resident by
//             capacity: grid 356 <= 2 blocks/CU * 256), and finishes its 128
//             samples -> one atomicAdd.
//  [256,356)  cdist[i] for class i; block i==0 also zeroes out[0] before its
//             fence+flag (finishers wait on all 100 cdist flags first).
__global__ __launch_bounds__(256, 2) void fused_all(
    const float* __restrict__ x, const int* __restrict__ targets,
    const float* __restrict__ centers, const float* __restrict__ cw,
    float* __restrict__ cdist, unsigned* __restrict__ cdone,
    unsigned* __restrict__ gflag, float* __restrict__ part,
    float* __restrict__ out) {
  __shared__ float sA[SAF];
  int b = blockIdx.x, tid = threadIdx.x;
  int wave = tid >> 6, lane = tid & 63;

  if (b < GEMM_BLOCKS) {
    // ================= gemm =================
    int mb = b >> 3, ks = b & 7;
    int koff = ks * KT;
    float* xs = sA;                      // [128][52]
    float* ws_t = sA + MT * XSP;         // [48][132] d-major: w
    float* as_t = ws_t + KT * CLS_PAD;   // [48][132] d-major: -2*w*c
    float* ts = as_t + KT * CLS_PAD;     // [100] per-class sum_d w*c^2 (block dims)

    #pragma unroll
    for (int r = 0; r < 8; r++) {        // xs: 128 rows x 12 float4
      int idx = tid + 256 * r;
      int row = idx >> 4, slot = idx & 15;
      if (slot < 12) {
        float4 v = *(const float4*)(x + (mb * MT + row) * ND + koff + 4 * slot);
        *(float4*)&xs[row * XSP + 4 * slot] = v;
      }
    }
    for (int r = 0; r < 19; r++) {       // class data: coalesced read, d-major write
      int idx = tid + 256 * r;
      if (idx < NC * KT) {
        int k = idx / KT, d = idx - k * KT;
        float w = exp2f(cw[k * ND + koff + d]);
        float c = centers[k * ND + koff + d];
        ws_t[d * CLS_PAD + k] = w;
        as_t[d * CLS_PAD + k] = -2.f * w * c;
      }
    }
    __syncthreads();
    if (tid < NC) {                      // ts[k] = sum_d w*c^2 = sum (as^2/(4w))
      float s = 0.f;
      for (int d = 0; d < KT; d++) {
        float av = as_t[d * CLS_PAD + tid];
        float wv = ws_t[d * CLS_PAD + tid];
        s += 0.25f * av * av / wv;
      }
      ts[tid] = s;
    }

    int cg = tid & 31, sg = tid >> 5;    // classes 4cg..4cg+3; samples sg+8m
    float acc[16][4];
    #pragma unroll
    for (int m = 0; m < 16; m++)
      #pragma unroll
      for (int u = 0; u < 4; u++) acc[m][u] = 0.f;

    #pragma unroll 1
    for (int d4 = 0; d4 < KT; d4 += 4) {
      float wv[4][4], av[4][4], xv[16][4];
      #pragma unroll
      for (int i2 = 0; i2 < 4; i2++) {
        *(float4*)&wv[i2][0] = *(const float4*)&ws_t[(d4 + i2) * CLS_PAD + 4 * cg];
        *(float4*)&av[i2][0] = *(const float4*)&as_t[(d4 + i2) * CLS_PAD + 4 * cg];
      }
      #pragma unroll
      for (int m = 0; m < 16; m++)
        *(float4*)&xv[m][0] = *(const float4*)&xs[(sg + 8 * m) * XSP + d4];
      #pragma unroll
      for (int i2 = 0; i2 < 4; i2++) {
        #pragma unroll
        for (int m = 0; m < 16; m++) {
          float xval = xv[m][i2];
          #pragma unroll
          for (int u = 0; u < 4; u++)
            acc[m][u] = fmaf(xval, fmaf(xval, wv[i2][u], av[i2][u]), acc[m][u]);
        }
      }
    }
    __syncthreads();  // ts fully written before epilogue reads it
    if (cg < 25) {    // class slots 4cg..4cg+3 all < 100
      float4 t4 = *(float4*)&ts[4 * cg];
      #pragma unroll
      for (int m = 0; m < 16; m++) {
        int i = mb * MT + sg + 8 * m;
        float4 v;
        v.x = acc[m][0] + t4.x; v.y = acc[m][1] + t4.y;
        v.z = acc[m][2] + t4.z; v.w = acc[m][3] + t4.w;
        *(float4*)&part[(ks * NB + i) * PPR + 4 * cg] = v;
      }
    }
    __threadfence();     // release partials
    __syncthreads();     // all threads' stores fenced before flag
    if (tid == 0) atomicExch(&gflag[b], MAGIC);

    if (ks == 7) {
      // ================= finisher for mb-group =================
      unsigned* msk = (unsigned*)sA;     // LDS reuse (post-barrier)
      float* ls = sA + 8;
      __syncthreads();
      if (tid < 4) msk[tid] = 0u;
      __syncthreads();
      #pragma unroll
      for (int r = 0; r < 16; r++) {     // presence mask from all 4096 targets
        int t = targets[tid + 256 * r];
        atomicOr(&msk[t >> 5], 1u << (t & 31));
      }
      if (tid < 7) {                     // poll sibling partial flags
        while (atomicCAS(&gflag[mb * 8 + tid], 0u, 0u) != MAGIC)
          __builtin_amdgcn_s_sleep(1);
      } else if (tid < 7 + NC) {         // poll cdist flags
        while (atomicCAS(&cdone[tid - 7], 0u, 0u) != MAGIC)
          __builtin_amdgcn_s_sleep(1);
      }
      __syncthreads();
      __threadfence();                   // acquire: invalidate stale cache lines

      int i = mb * MT + (tid >> 1);      // 2 threads per sample
      int h = tid & 1;                   // class-quad halves: 13 + 12
      int ti = targets[i];
      float cc = cdist[ti];
      float an = 1e30f, ap = 0.f;
      int kq0 = h ? 13 : 0, kq1 = h ? 25 : 13;
      for (int kq = kq0; kq < kq1; kq++) {
        float4 d2 = make_float4(0.f, 0.f, 0.f, 0.f);
        #pragma unroll
        for (int s = 0; s < KS; s++) {
          float4 p = *(const float4*)(part + (s * NB + i) * PPR + 4 * kq);
          d2.x += p.x; d2.y += p.y; d2.z += p.z; d2.w += p.w;
        }
        float dd[4] = {d2.x, d2.y, d2.z, d2.w};
        #pragma unroll
        for (int j = 0; j < 4; j++) {
          int k = 4 * kq + j;
          float dist = sqrtf(fmaxf(dd[j], 1e-12f));
          bool pres = (msk[k >> 5] >> (k & 31)) & 1u;
          if (k == ti) ap = dist;
          else if (pres) an = fminf(an, dist);
        }
      }
      an = fminf(an, __shfl_xor(an, 1, 64));   // merge the h-pair
      ap = fmaxf(ap, __shfl_xor(ap, 1, 64));
      float loss = ap + ((an >= cc) ? 0.f : cc - an);
      #pragma unroll
      for (int off = 32; off; off >>= 1) loss += __shfl_xor(loss, off, 64);
      if (lane == 0) ls[wave] = loss;
      __syncthreads();
      if (tid == 0) {
        float tsum = (ls[0] + ls[1] + ls[2] + ls[3]) * 0.5f;  // pair double-count
        atomicAdd(out, tsum * (1.0f / NB));
      }
    }
  } else {
    // ================= cdist for class i =================
    int i = b - GEMM_BLOCKS;
    float* ci_s = sA;
    float* wi_s = sA + ND;
    float* sred = sA + 2 * ND;
    if (i == 0 && tid == 255) out[0] = 0.f;  // before fence+flag; finishers wait
    for (int d = tid; d < ND; d += 256) {
      ci_s[d] = centers[i * ND + d];
      wi_s[d] = exp2f(cw[i * ND + d]);
    }
    __syncthreads();
    float minv = 1e30f;
    for (int s4 = 0; s4 < 24; s4 += 4) {   // wave handles j = wave + 4*s
      float red[4];
      #pragma unroll
      for (int u = 0; u < 4; u++) {
        int j = wave + 4 * (s4 + u);
        float acc = 0.f;
        #pragma unroll
        for (int e = 0; e < 6; e++) {
          int d = lane + 64 * e;
          float df = ci_s[d] - centers[j * ND + d];
          acc = fmaf(wi_s[d] * df, df, acc);
        }
        red[u] = acc;
      }
      #pragma unroll
      for (int off = 32; off; off >>= 1) {
        #pragma unroll
        for (int u = 0; u < 4; u++) red[u] += __shfl_xor(red[u], off, 64);
      }
      #pragma unroll
      for (int u = 0; u < 4; u++) {
        int j = wave + 4 * (s4 + u);
        if (j != i) minv = fminf(minv, red[u]);
      }
    }
    {  // tail: j = wave + 96
      int j = wave + 96;
      float acc = 0.f;
      #pragma unroll
      for (int e = 0; e < 6; e++) {
        int d = lane + 64 * e;
        float df = ci_s[d] - centers[j * ND + d];
        acc = fmaf(wi_s[d] * df, df, acc);
      }
      #pragma unroll
      for (int off = 32; off; off >>= 1) acc += __shfl_xor(acc, off, 64);
      if (j != i) minv = fminf(minv, acc);
    }
    if (lane == 0) sred[wave] = minv;
    __syncthreads();
    if (tid == 0)
      cdist[i] = sqrtf(fminf(fminf(sred[0], sred[1]), fminf(sred[2], sred[3])));
    __threadfence();   // release cdist[i] (and out[0] for i==0)
    __syncthreads();
    if (tid == 0) atomicExch(&cdone[i], MAGIC);
  }
}

extern "C" void kernel_launch(void* const* d_in, const int* in_sizes, int n_in,
                              void* d_out, int out_size, void* d_ws, size_t ws_size,
                              hipStream_t stream) {
  const float* inputs  = (const float*)d_in[0];
  const int*   targets = (const int*)d_in[1];
  // d_in[2] = epoch_number (unused by the reference math)
  const float* centers = (const float*)d_in[3];
  const float* cw      = (const float*)d_in[4];
  float* out = (float*)d_out;

  float* cdist     = (float*)d_ws;                 // [128]
  unsigned* cdone  = (unsigned*)(cdist + 128);     // [128] flags (poison != MAGIC)
  unsigned* gflag  = cdone + 128;                  // [256] flags
  float* part      = (float*)(gflag + 256);        // [8*4096*100] = 13.1 MB

  fused_all<<<GRID, 256, 0, stream>>>(inputs, targets, centers, cw, cdist,
                                      cdone, gflag, part, out);
}